// Round 17
// baseline (580.239 us; speedup 1.0000x reference)
//
#include <hip/hip_runtime.h>

#define NB 16
#define NL 1024
#define ND 64
#define NW 20
#define CH 16                   // l's per block (rolling)
#define THR 0.3f
#define REP_UPD 60
#define REP_EPI 10

typedef float f32x4 __attribute__((ext_vector_type(4)));

// ================= DIAGNOSTIC ROUND 2 (R17) =================
// R14: compute ~51-57us @97% VALUBusy vs static model ~15-20us (3x mystery).
// R16's bundled rewrite regressed (+30us) — revert to R15, split compute
// finer: update-only vs epilogue+update. Real R15 kernel runs last.

#define STAGE_WIN()                                                        \
    const int NROW = NW - 1 + CH;                                          \
    __shared__ float win[NW - 1 + CH][ND];                                 \
    {                                                                      \
        const float* xb = x + ((size_t)b * NL) * ND;                       \
        _Pragma("unroll")                                                  \
        for (int i = 0; i < 3; ++i) {                                      \
            int s = t + i * 256;                                           \
            if (s < NROW * 16) {                                           \
                int w    = s >> 4;                                         \
                int c4   = (s & 15) << 2;                                  \
                int lsrc = l0 - (NW - 1) + w;                              \
                f32x4 v = {0.f, 0.f, 0.f, 0.f};                            \
                if (lsrc >= 0) v = *(const f32x4*)&xb[(size_t)lsrc * ND + c4]; \
                *(f32x4*)&win[w][c4] = v;                                  \
            }                                                              \
        }                                                                  \
    }                                                                      \
    __syncthreads();

#define INIT_STATS()                                                       \
    _Pragma("unroll")                                                      \
    for (int w = 0; w < NW; ++w) {                                         \
        float ar[4];                                                       \
        ar[0] = win[w][r0];                                                \
        ar[1] = win[w][r0 + 4];                                            \
        ar[2] = win[w][r0 + 8];                                            \
        ar[3] = win[w][r0 + 12];                                           \
        f32x4 b0 = *(const f32x4*)&win[w][e0];                             \
        float br[4] = {b0.x, b0.y, b0.z, b0.w};                            \
        _Pragma("unroll")                                                  \
        for (int i = 0; i < 4; ++i) {                                      \
            rs[i] += ar[i];                                                \
            rq[i]  = fmaf(ar[i], ar[i], rq[i]);                            \
            _Pragma("unroll")                                              \
            for (int j = 0; j < 4; ++j)                                    \
                acc[i][j] = fmaf(ar[i], br[j], acc[i][j]);                 \
        }                                                                  \
        _Pragma("unroll")                                                  \
        for (int j = 0; j < 4; ++j) {                                      \
            cs[j] += br[j];                                                \
            cq[j]  = fmaf(br[j], br[j], cq[j]);                            \
        }                                                                  \
    }

#define UPDATE_BODY(s)                                                     \
    {                                                                      \
        float an[4], ao[4];                                                \
        an[0] = win[(s) + NW][r0];                                         \
        an[1] = win[(s) + NW][r0 + 4];                                     \
        an[2] = win[(s) + NW][r0 + 8];                                     \
        an[3] = win[(s) + NW][r0 + 12];                                    \
        ao[0] = win[(s)][r0];                                              \
        ao[1] = win[(s)][r0 + 4];                                          \
        ao[2] = win[(s)][r0 + 8];                                          \
        ao[3] = win[(s)][r0 + 12];                                         \
        f32x4 nb  = *(const f32x4*)&win[(s) + NW][e0];                     \
        f32x4 obv = *(const f32x4*)&win[(s)][e0];                          \
        float bn[4] = {nb.x, nb.y, nb.z, nb.w};                            \
        float bo[4] = {obv.x, obv.y, obv.z, obv.w};                        \
        _Pragma("unroll")                                                  \
        for (int i = 0; i < 4; ++i) {                                      \
            rs[i] += an[i] - ao[i];                                        \
            rq[i]  = fmaf(an[i], an[i], fmaf(-ao[i], ao[i], rq[i]));       \
            _Pragma("unroll")                                              \
            for (int j = 0; j < 4; ++j)                                    \
                acc[i][j] = fmaf(an[i], bn[j], fmaf(-ao[i], bo[j], acc[i][j])); \
        }                                                                  \
        _Pragma("unroll")                                                  \
        for (int j = 0; j < 4; ++j) {                                      \
            cs[j] += bn[j] - bo[j];                                        \
            cq[j]  = fmaf(bn[j], bn[j], fmaf(-bo[j], bo[j], cq[j]));       \
        }                                                                  \
    }

#define CHECKSUM_KEEP()                                                    \
    {                                                                      \
        float chk = 0.f;                                                   \
        _Pragma("unroll")                                                  \
        for (int i = 0; i < 4; ++i)                                        \
            chk += rs[i] + rq[i] + cs[i] + cq[i];                          \
        _Pragma("unroll")                                                  \
        for (int i = 0; i < 4; ++i)                                        \
            _Pragma("unroll")                                              \
            for (int j = 0; j < 4; ++j) chk += acc[i][j];                  \
        asm volatile("" :: "v"(chk));                                      \
    }

// --- (1) rolling update only ---
__global__ void upd_only_kernel(const float* __restrict__ x)
{
    const int blk = blockIdx.x;
    const int b   = blk >> 6;
    const int l0  = (blk & 63) * CH;
    const int t   = threadIdx.x;
    STAGE_WIN();
    const int q  = t >> 6;
    const int g  = (t >> 4) & 3;
    const int tc = t & 15;
    const int r0 = (q << 4) + g;
    const int e0 = tc << 2;
    float acc[4][4] = {};
    float rs[4] = {}, rq[4] = {};
    float cs[4] = {}, cq[4] = {};
    INIT_STATS();
    for (int r = 0; r < REP_UPD; ++r) {
        rs[0] += (float)r * 1e-30f;
        #pragma unroll 2
        for (int s = 0; s < CH - 1; ++s) {
            UPDATE_BODY(s);
        }
        CHECKSUM_KEEP();
    }
}

// --- (2) epilogue + update (R15-exact epilogue, asm-kept) ---
__global__ void epiupd_kernel(const float* __restrict__ x)
{
    const int blk = blockIdx.x;
    const int b   = blk >> 6;
    const int l0  = (blk & 63) * CH;
    const int t   = threadIdx.x;
    STAGE_WIN();
    const int q  = t >> 6;
    const int g  = (t >> 4) & 3;
    const int tc = t & 15;
    const int r0 = (q << 4) + g;
    const int e0 = tc << 2;
    float acc[4][4] = {};
    float rs[4] = {}, rq[4] = {};
    float cs[4] = {}, cq[4] = {};
    INIT_STATS();
    const float invW  = 1.0f / NW;
    const float EPS19 = 19e-8f;
    for (int r = 0; r < REP_EPI; ++r) {
        rs[0] += (float)r * 1e-30f;
        #pragma unroll 2
        for (int s = 0; s < CH; ++s) {
            float sdu[4], seu[4], mc[4];
            #pragma unroll
            for (int i = 0; i < 4; ++i) {
                float qv = fmaf(-rs[i] * invW, rs[i], rq[i]);
                sdu[i] = __builtin_amdgcn_sqrtf(qv);
            }
            #pragma unroll
            for (int j = 0; j < 4; ++j) {
                mc[j] = cs[j] * invW;
                float qv = fmaf(-cs[j], mc[j], cq[j]);
                seu[j] = __builtin_amdgcn_sqrtf(qv);
            }
            #pragma unroll
            for (int i = 0; i < 4; ++i) {
                f32x4 o;
                float cv, rr;
                cv = fmaf(-rs[i], mc[0], acc[i][0]);
                rr = __builtin_amdgcn_rcpf(fmaf(sdu[i], seu[0], EPS19));
                o.x = fmaxf(fmaf(fabsf(cv), rr, -THR), 0.0f);
                cv = fmaf(-rs[i], mc[1], acc[i][1]);
                rr = __builtin_amdgcn_rcpf(fmaf(sdu[i], seu[1], EPS19));
                o.y = fmaxf(fmaf(fabsf(cv), rr, -THR), 0.0f);
                cv = fmaf(-rs[i], mc[2], acc[i][2]);
                rr = __builtin_amdgcn_rcpf(fmaf(sdu[i], seu[2], EPS19));
                o.z = fmaxf(fmaf(fabsf(cv), rr, -THR), 0.0f);
                cv = fmaf(-rs[i], mc[3], acc[i][3]);
                rr = __builtin_amdgcn_rcpf(fmaf(sdu[i], seu[3], EPS19));
                o.w = fmaxf(fmaf(fabsf(cv), rr, -THR), 0.0f);
                asm volatile("" :: "v"(o.x), "v"(o.y), "v"(o.z), "v"(o.w));
            }
            if (s < CH - 1) {
                UPDATE_BODY(s);
            }
        }
        CHECKSUM_KEEP();
    }
}

// --- (3) real kernel: R15 verbatim (best known, 56.3us) ---
__global__ void dyn_corr_kernel(
    const float* __restrict__ x, float* __restrict__ out)
{
    const int blk = blockIdx.x;
    const int b   = blk >> 6;
    const int l0  = (blk & 63) * CH;
    const int t   = threadIdx.x;
    STAGE_WIN();
    const int q  = t >> 6;
    const int g  = (t >> 4) & 3;
    const int tc = t & 15;
    const int r0 = (q << 4) + g;
    const int e0 = tc << 2;

    float acc[4][4] = {};
    float rs[4] = {}, rq[4] = {};
    float cs[4] = {}, cq[4] = {};
    INIT_STATS();

    const float invW  = 1.0f / NW;
    const float EPS19 = 19e-8f;
    float* obase = out + ((size_t)b * NL + l0) * (ND * ND);

    #pragma unroll 2
    for (int s = 0; s < CH; ++s) {
        float sdu[4], seu[4], mc[4];
        #pragma unroll
        for (int i = 0; i < 4; ++i) {
            float qv = fmaf(-rs[i] * invW, rs[i], rq[i]);
            sdu[i] = __builtin_amdgcn_sqrtf(qv);
        }
        #pragma unroll
        for (int j = 0; j < 4; ++j) {
            mc[j] = cs[j] * invW;
            float qv = fmaf(-cs[j], mc[j], cq[j]);
            seu[j] = __builtin_amdgcn_sqrtf(qv);
        }
        float* ob = obase + (size_t)s * (ND * ND);
        #pragma unroll
        for (int i = 0; i < 4; ++i) {
            f32x4 o;
            float cv, rr;
            cv = fmaf(-rs[i], mc[0], acc[i][0]);
            rr = __builtin_amdgcn_rcpf(fmaf(sdu[i], seu[0], EPS19));
            o.x = fmaxf(fmaf(fabsf(cv), rr, -THR), 0.0f);
            cv = fmaf(-rs[i], mc[1], acc[i][1]);
            rr = __builtin_amdgcn_rcpf(fmaf(sdu[i], seu[1], EPS19));
            o.y = fmaxf(fmaf(fabsf(cv), rr, -THR), 0.0f);
            cv = fmaf(-rs[i], mc[2], acc[i][2]);
            rr = __builtin_amdgcn_rcpf(fmaf(sdu[i], seu[2], EPS19));
            o.z = fmaxf(fmaf(fabsf(cv), rr, -THR), 0.0f);
            cv = fmaf(-rs[i], mc[3], acc[i][3]);
            rr = __builtin_amdgcn_rcpf(fmaf(sdu[i], seu[3], EPS19));
            o.w = fmaxf(fmaf(fabsf(cv), rr, -THR), 0.0f);
            __builtin_nontemporal_store(o, (f32x4*)&ob[(r0 + 4 * i) * ND + e0]);
        }
        if (s < CH - 1) {
            UPDATE_BODY(s);
        }
    }
}

extern "C" void kernel_launch(void* const* d_in, const int* in_sizes, int n_in,
                              void* d_out, int out_size, void* d_ws, size_t ws_size,
                              hipStream_t stream) {
    const float* x = (const float*)d_in[0];
    float* out = (float*)d_out;
    dim3 grid(NB * (NL / CH));
    dim3 block(256);
    hipLaunchKernelGGL(upd_only_kernel, grid, block, 0, stream, x);
    hipLaunchKernelGGL(epiupd_kernel, grid, block, 0, stream, x);
    hipLaunchKernelGGL(dyn_corr_kernel, grid, block, 0, stream, x, out);
}

// Round 18
// 94.393 us; speedup vs baseline: 6.1471x; 6.1471x over previous
//
#include <hip/hip_runtime.h>

#define NB 16
#define NL 1024
#define ND 64
#define NW 20
#define CH 16                   // l's per block (rolling)
#define THR 0.3f
#define REP_STORE 8

typedef float f32x4 __attribute__((ext_vector_type(4)));

// ============ R18: settle Model A (WAR-serialized stores) vs Model B
// ============ (pattern BW cap) in one round.
// R17 ablation: slim compute = ~19us total (upd 5.95us/rep, epi ~10.7us/rep)
// => real 56.3us is either 39us stores + 17us exposed compute (A) or a
// 4.8 TB/s store-pattern cap with compute hidden (B).
// (1) store_only x8 (~2.1GB) -> unambiguous bare-pattern BW in top-5.
// (2) real kernel = R15 with unroll 4 (4 rotating o-reg sets widen the WAR
//     vmcnt slack to 3 steps) -> Model A's fix, null under Model B.

// --- (1) bare store pattern, R12/R15 addresses, x8 ---
__global__ void store_only_kernel(const float* __restrict__ x,
                                  float* __restrict__ out)
{
    const int blk = blockIdx.x;            // 0..1023
    const int b   = blk >> 6;
    const int l0  = (blk & 63) * CH;
    const int t   = threadIdx.x;
    const int q   = t >> 6;
    const int g   = (t >> 4) & 3;
    const int tc  = t & 15;
    const int r0  = (q << 4) + g;
    const int e0  = tc << 2;

    f32x4 v = *(const f32x4*)&x[(size_t)((blk * 256 + t) & 65535) * 4];
    float* obase = out + ((size_t)b * NL + l0) * (ND * ND);

    for (int r = 0; r < REP_STORE; ++r) {
        v.x += 1.0f;                       // defeat cross-rep CSE
        for (int s = 0; s < CH; ++s) {
            float* ob = obase + (size_t)s * (ND * ND);
            #pragma unroll
            for (int i = 0; i < 4; ++i) {
                __builtin_nontemporal_store(v, (f32x4*)&ob[(r0 + 4 * i) * ND + e0]);
            }
        }
    }
}

// --- (2) real kernel: R15 + unroll 4 ---
__global__ void dyn_corr_kernel(
    const float* __restrict__ x, float* __restrict__ out)
{
    const int blk = blockIdx.x;            // 0..1023
    const int b   = blk >> 6;
    const int l0  = (blk & 63) * CH;
    const int t   = threadIdx.x;           // 0..255

    const int NROW = NW - 1 + CH;          // 35 staged rows
    __shared__ float win[NW - 1 + CH][ND]; // 8960 B, raw (uncentered)

    const float* xb = x + ((size_t)b * NL) * ND;

    #pragma unroll
    for (int i = 0; i < 3; ++i) {
        int s = t + i * 256;               // valid < 560
        if (s < NROW * 16) {
            int w    = s >> 4;
            int c4   = (s & 15) << 2;
            int lsrc = l0 - (NW - 1) + w;
            f32x4 v = {0.f, 0.f, 0.f, 0.f};
            if (lsrc >= 0) v = *(const f32x4*)&xb[(size_t)lsrc * ND + c4];
            *(f32x4*)&win[w][c4] = v;
        }
    }
    __syncthreads();                       // win read-only from here on

    const int q  = t >> 6;                 // wave 0..3 -> rows 16q..16q+15
    const int g  = (t >> 4) & 3;           // row-group within wave
    const int tc = t & 15;                 // col group
    const int r0 = (q << 4) + g;           // row(i) = r0 + 4*i
    const int e0 = tc << 2;                // cols e0..e0+3

    float acc[4][4] = {};                  // raw Gram tile (row i, col j)
    float rs[4] = {}, rq[4] = {};          // row sum / sumsq
    float cs[4] = {}, cq[4] = {};          // col sum / sumsq

    #pragma unroll
    for (int w = 0; w < NW; ++w) {
        float ar[4];
        ar[0] = win[w][r0];
        ar[1] = win[w][r0 + 4];
        ar[2] = win[w][r0 + 8];
        ar[3] = win[w][r0 + 12];
        f32x4 b0 = *(const f32x4*)&win[w][e0];
        float br[4] = {b0.x, b0.y, b0.z, b0.w};
        #pragma unroll
        for (int i = 0; i < 4; ++i) {
            rs[i] += ar[i];
            rq[i]  = fmaf(ar[i], ar[i], rq[i]);
            #pragma unroll
            for (int j = 0; j < 4; ++j)
                acc[i][j] = fmaf(ar[i], br[j], acc[i][j]);
        }
        #pragma unroll
        for (int j = 0; j < 4; ++j) {
            cs[j] += br[j];
            cq[j]  = fmaf(br[j], br[j], cq[j]);
        }
    }

    const float invW  = 1.0f / NW;
    const float EPS19 = 19e-8f;            // 19 * 1e-8 (rescaled ref eps)
    float* obase = out + ((size_t)b * NL + l0) * (ND * ND);

    #pragma unroll 4
    for (int s = 0; s < CH; ++s) {
        float sdu[4], seu[4], mc[4];
        #pragma unroll
        for (int i = 0; i < 4; ++i) {
            float qv = fmaf(-rs[i] * invW, rs[i], rq[i]);
            sdu[i] = __builtin_amdgcn_sqrtf(qv);
        }
        #pragma unroll
        for (int j = 0; j < 4; ++j) {
            mc[j] = cs[j] * invW;
            float qv = fmaf(-cs[j], mc[j], cq[j]);
            seu[j] = __builtin_amdgcn_sqrtf(qv);
        }
        float* ob = obase + (size_t)s * (ND * ND);
        #pragma unroll
        for (int i = 0; i < 4; ++i) {
            f32x4 o;
            float cv, rr;
            cv = fmaf(-rs[i], mc[0], acc[i][0]);
            rr = __builtin_amdgcn_rcpf(fmaf(sdu[i], seu[0], EPS19));
            o.x = fmaxf(fmaf(fabsf(cv), rr, -THR), 0.0f);
            cv = fmaf(-rs[i], mc[1], acc[i][1]);
            rr = __builtin_amdgcn_rcpf(fmaf(sdu[i], seu[1], EPS19));
            o.y = fmaxf(fmaf(fabsf(cv), rr, -THR), 0.0f);
            cv = fmaf(-rs[i], mc[2], acc[i][2]);
            rr = __builtin_amdgcn_rcpf(fmaf(sdu[i], seu[2], EPS19));
            o.z = fmaxf(fmaf(fabsf(cv), rr, -THR), 0.0f);
            cv = fmaf(-rs[i], mc[3], acc[i][3]);
            rr = __builtin_amdgcn_rcpf(fmaf(sdu[i], seu[3], EPS19));
            o.w = fmaxf(fmaf(fabsf(cv), rr, -THR), 0.0f);
            __builtin_nontemporal_store(o, (f32x4*)&ob[(r0 + 4 * i) * ND + e0]);
        }
        if (s < CH - 1) {
            float an[4], ao[4];
            an[0] = win[s + NW][r0];
            an[1] = win[s + NW][r0 + 4];
            an[2] = win[s + NW][r0 + 8];
            an[3] = win[s + NW][r0 + 12];
            ao[0] = win[s][r0];
            ao[1] = win[s][r0 + 4];
            ao[2] = win[s][r0 + 8];
            ao[3] = win[s][r0 + 12];
            f32x4 nb  = *(const f32x4*)&win[s + NW][e0];
            f32x4 obv = *(const f32x4*)&win[s][e0];
            float bn[4] = {nb.x, nb.y, nb.z, nb.w};
            float bo[4] = {obv.x, obv.y, obv.z, obv.w};
            #pragma unroll
            for (int i = 0; i < 4; ++i) {
                rs[i] += an[i] - ao[i];
                rq[i]  = fmaf(an[i], an[i], fmaf(-ao[i], ao[i], rq[i]));
                #pragma unroll
                for (int j = 0; j < 4; ++j)
                    acc[i][j] = fmaf(an[i], bn[j], fmaf(-ao[i], bo[j], acc[i][j]));
            }
            #pragma unroll
            for (int j = 0; j < 4; ++j) {
                cs[j] += bn[j] - bo[j];
                cq[j]  = fmaf(bn[j], bn[j], fmaf(-bo[j], bo[j], cq[j]));
            }
        }
    }
}

extern "C" void kernel_launch(void* const* d_in, const int* in_sizes, int n_in,
                              void* d_out, int out_size, void* d_ws, size_t ws_size,
                              hipStream_t stream) {
    const float* x = (const float*)d_in[0];
    float* out = (float*)d_out;
    dim3 grid(NB * (NL / CH));
    dim3 block(256);
    // store_only scribbles d_out; real kernel overwrites all of it correctly
    hipLaunchKernelGGL(store_only_kernel, grid, block, 0, stream, x, out);
    hipLaunchKernelGGL(dyn_corr_kernel, grid, block, 0, stream, x, out);
}